// Round 5
// baseline (2303.779 us; speedup 1.0000x reference)
//
#include <hip/hip_runtime.h>
#include <cstdint>
#include <cstddef>

typedef __attribute__((ext_vector_type(8))) short short8;   // 8 bf16 (4 VGPRs)
typedef __attribute__((ext_vector_type(4))) short bfx4;     // 4 bf16 (8 B)
typedef __attribute__((ext_vector_type(4))) float f32x4;

#define HH     100
#define G4     400
#define NCOL   416          // 400 gates + 5 logits + 11 pad = 26 tiles of 16
#define NTIL   26
#define KTN    3            // 3 k-tiles of 32 -> k<96 via MFMA
#define KRES   96           // k=96..99 residual in f32
#define BTOT   8192
#define TST    512
#define GR     16           // rows per phase-group; block owns 2 groups = 32 rows
#define NBLK   256
#define BLOCK  512          // 8 waves; G-crew w0-3, E-crew w4-7; 2 waves/SIMD -> 256 regs
#define ZW     420          // z row stride (words)
#define TANHC  1.5f
#define EPSF   1e-9f

__device__ unsigned short d_Bhi[NTIL*KTN*64*8];  // [W_h|W_ops|0] hi, B-frag order
__device__ unsigned short d_Blo[NTIL*KTN*64*8];  // lo residual
__device__ float d_Ep2[6*G4];                    // emb @ W_x   [e][cell][gate]
__device__ float d_WresG[NCOL*4];                // rows 96..99 of [W_h|W_ops|0], [n][q]
__device__ float d_Z0[(size_t)BTOT*G4];          // x0 @ W_x    [b][n]

static __device__ __forceinline__ unsigned short bf16hi(float f){
  unsigned u = __float_as_uint(f);
  return (unsigned short)((u + 0x7FFFu + ((u>>16)&1u)) >> 16);   // RNE
}
static __device__ __forceinline__ float bf16f(unsigned short s){
  return __uint_as_float(((unsigned)s)<<16);
}
static __device__ __forceinline__ float frcp(float x){ return __builtin_amdgcn_rcpf(x); }
static __device__ __forceinline__ float sigf(float x){ return frcp(1.0f + __expf(-x)); }
static __device__ __forceinline__ float tanh_f(float x){ return 1.0f - 2.0f*frcp(__expf(2.0f*x) + 1.0f); }

// ---- setup kernels (round-0 verbatim) ------------------------------------

// B-frag order for 16x16x32: n = tile*16 + (lane&15), k = kt*32 + (lane>>4)*8 + i
__global__ void setup_bpack(const float* __restrict__ Wh, const float* __restrict__ Wops){
  int idx = blockIdx.x*blockDim.x + threadIdx.x;     // NTIL*KTN*64 = 4992
  if (idx >= NTIL*KTN*64) return;
  int tile = idx/(KTN*64), rem = idx - tile*(KTN*64), kt = rem>>6, ln = rem&63;
  int n = tile*16 + (ln & 15);
  #pragma unroll
  for (int i = 0; i < 8; ++i){
    int k = kt*32 + (ln>>4)*8 + i;                   // k < 96 always
    float w = 0.f;
    if (n < G4)          w = Wh[k*G4 + n];
    else if (n < G4+5)   w = Wops[k*5 + (n - G4)];
    unsigned short hi = bf16hi(w);
    unsigned short lo = bf16hi(w - bf16f(hi));
    d_Bhi[idx*8+i] = hi;
    d_Blo[idx*8+i] = lo;
  }
}

__global__ void setup_misc(const float* __restrict__ emb, const float* __restrict__ Wx,
                           const float* __restrict__ Wh, const float* __restrict__ Wops){
  int idx = blockIdx.x*blockDim.x + threadIdx.x;
  if (idx < 6*G4){                                   // Ep2 [e][cell][gate]
    int e = idx/G4, r2 = idx - e*G4, je = r2>>2, g = r2&3;
    float s = 0.f;
    for (int k = 0; k < HH; ++k) s = fmaf(emb[e*HH+k], Wx[k*G4 + g*HH + je], s);
    d_Ep2[idx] = s;
  } else if (idx < 6*G4 + NCOL*4){                   // residual rows 96..99
    int i = idx - 6*G4, n = i>>2, q = i&3;
    float w = 0.f;
    if (n < G4)        w = Wh[(KRES+q)*G4 + n];
    else if (n < G4+5) w = Wops[(KRES+q)*5 + (n - G4)];
    d_WresG[i] = w;
  }
}

// Z0 = x0 @ W_x, stored [b][n]
__global__ __launch_bounds__(256) void setup_z0(const float* __restrict__ x0,
                                                const float* __restrict__ Wx){
  __shared__ float xs[64*101];
  const int bb = blockIdx.x * 64;                    // 128 blocks
  for (int i = threadIdx.x; i < 64*HH; i += 256){
    int r = i/HH, k = i - r*HH;
    xs[r*101 + k] = x0[(size_t)(bb + r)*HH + k];
  }
  __syncthreads();
  const int bl = threadIdx.x & 63;
  for (int ng = threadIdx.x >> 6; ng < HH; ng += 4){
    f32x4 a = {0.f,0.f,0.f,0.f};
    for (int k = 0; k < HH; ++k){
      f32x4 w = *(const f32x4*)&Wx[k*G4 + ng*4];
      a += w * xs[bl*101 + k];
    }
    *(f32x4*)&d_Z0[(size_t)(bb + bl)*G4 + ng*4] = a;
  }
}

// ---- main persistent kernel ---------------------------------------------
// 256 blocks x 32 rows (A=rows 0..15, B=16..31), 8 waves, WAVE-SPECIALIZED:
//   G-crew = waves 0..3 (tiles 7/7/7/5; wave3 holds logits tile 25 + sampler)
//   E-crew = waves 4..7 (400 4-cell tasks/group; w4-6: 2 tasks, w7: 1 + gumbel)
// Each SIMD hosts 1 G-wave + 1 E-wave -> MFMA and VALU/trans co-issue (m114).
// Round-2's verified phase schedule (2 barriers/step), round-4's verified math:
//   phase(0,t): G(A,t)+sample(A,t-1)  ||  E(B,t-1) + gn(B,u[t-1])
//   phase(1,t): G(B,t)+sample(B,t-1)  ||  E(A,t)   + gn(A,u[t])
// launch_bounds(512,2): 256-reg budget; G-crew ~230 regs (B-frags 168) fits.

__global__ __launch_bounds__(BLOCK, 2) void rnn_main(
    const float* __restrict__ u, float* __restrict__ out)
{
  __shared__ __align__(16) float zh[2][GR*ZW];                  // 53760 B
  __shared__ __align__(16) unsigned short fhi[2][KTN*64*8];     //  6144 B
  __shared__ __align__(16) unsigned short flo[2][KTN*64*8];     //  6144 B
  __shared__ __align__(16) float h_res[2][4*GR];                //   512 B [q][r]
  __shared__ __align__(16) float Ep2_l[6*G4];                   //  9600 B
  __shared__ __align__(16) float Wres_l[NCOL*4];                //  6656 B
  __shared__ __align__(16) float gn_lds[2][GR*5];               //   640 B
  __shared__ int op_lds[2][GR];                                 //   128 B

  const int tid  = threadIdx.x;
  const int wave = tid >> 6;
  const int lane = tid & 63;
  const int cn   = lane & 15;
  const int q4   = lane >> 4;
  const int row0 = blockIdx.x * (2*GR);
  const int et   = tid - 256;       // E-crew index (waves 4..7)

  for (int i = tid; i < 6*G4;   i += BLOCK) Ep2_l[i]  = d_Ep2[i];
  for (int i = tid; i < NCOL*4; i += BLOCK) Wres_l[i] = d_WresG[i];

  // persistent B-fragments (G-crew): w0:0-6, w1:7-13, w2:14-20, w3:21-25
  const int tb  = wave*7;
  const int ntl = (wave==3) ? 5 : 7;
  short8 bh[7][KTN], bl[7][KTN];
  if (wave < 4){
    const short8* bph = (const short8*)d_Bhi;
    const short8* bpl = (const short8*)d_Blo;
    #pragma unroll
    for (int tl = 0; tl < 7; ++tl) if (tl < ntl)
      #pragma unroll
      for (int kt = 0; kt < KTN; ++kt){
        int fi = ((tb+tl)*KTN + kt)*64 + lane;
        bh[tl][kt] = bph[fi];
        bl[tl][kt] = bpl[fi];
      }
  }

  float csA[2][4] = {{0.f,0.f,0.f,0.f},{0.f,0.f,0.f,0.f}};  // c-state per (group,task)
  float csB[2][4] = {{0.f,0.f,0.f,0.f},{0.f,0.f,0.f,0.f}};
  float lpA=0.f, entA=0.f, lpB=0.f, entB=0.f;

  __syncthreads();

  auto phase = [&](int gG, int t, float (&cs)[2][4], float& lp, float& ent){
    const int  gE    = gG ^ 1;
    const bool stage = (t == 0);
    const bool doE   = gG ? (t < TST) : (t >= 1);
    const bool addE  = gG ? (t >= 1)  : (t >= 2);
    const bool gnDo  = gG ? (t < TST) : (t >= 1);
    const int  uT    = gG ? t : (t-1);

    if (wave < 4){
      // =============== G-crew ===============
      if (stage){
        for (int k = tid; k < GR*HH; k += 256){
          int r = k/HH, c4 = k - r*HH;
          *(f32x4*)&zh[gG][r*ZW + c4*4] =
            *(const f32x4*)&d_Z0[(size_t)(row0 + gG*GR + r)*G4 + c4*4];
        }
      } else {
        short8 ah[KTN], al[KTN];                     // A-frags: h of group gG
        #pragma unroll
        for (int kt = 0; kt < KTN; ++kt){
          ah[kt] = *(const short8*)&fhi[gG][(kt*64 + lane)*8];
          al[kt] = *(const short8*)&flo[gG][(kt*64 + lane)*8];
        }
        f32x4 hq[4];
        #pragma unroll
        for (int q = 0; q < 4; ++q)                  // broadcast reads [q][r]
          hq[q] = *(const f32x4*)&h_res[gG][q*GR + q4*4];
        #pragma unroll
        for (int tl = 0; tl < 7; ++tl) if (tl < ntl){
          const int n = (tb+tl)*16 + cn;
          f32x4 acc = {0.f,0.f,0.f,0.f};
          #pragma unroll
          for (int kt = 0; kt < KTN; ++kt){
            acc = __builtin_amdgcn_mfma_f32_16x16x32_bf16(ah[kt], bh[tl][kt], acc, 0,0,0);
            acc = __builtin_amdgcn_mfma_f32_16x16x32_bf16(al[kt], bh[tl][kt], acc, 0,0,0);
            acc = __builtin_amdgcn_mfma_f32_16x16x32_bf16(ah[kt], bl[tl][kt], acc, 0,0,0);
            acc = __builtin_amdgcn_mfma_f32_16x16x32_bf16(al[kt], bl[tl][kt], acc, 0,0,0);
          }
          f32x4 wr = *(const f32x4*)&Wres_l[n*4];
          #pragma unroll
          for (int q = 0; q < 4; ++q) acc += hq[q] * wr[q];
          #pragma unroll
          for (int i = 0; i < 4; ++i)                // C: row=q4*4+i, col=n
            zh[gG][(q4*4+i)*ZW + n] = acc[i];
        }
        // ---- sampling for step t-1 (wave 3; same-wave dep on its tile-25 stores) ----
        if (wave == 3 && lane < 16){
          const int r = lane;
          f32x4 l4 = *(const f32x4*)&zh[gG][r*ZW + 400];
          float l5v = zh[gG][r*ZW + 404];
          float l0 = TANHC*tanh_f(l4.x), l1 = TANHC*tanh_f(l4.y);
          float l2 = TANHC*tanh_f(l4.z), l3 = TANHC*tanh_f(l4.w);
          float l4v = TANHC*tanh_f(l5v);
          float lv[5] = {l0,l1,l2,l3,l4v};
          int op = 0; float best = -1e30f, lop = l0;
          #pragma unroll
          for (int o = 0; o < 5; ++o){
            float v = lv[o] + gn_lds[gG][r*5 + o];
            if (v > best){ best = v; op = o; lop = lv[o]; }   // strict >: first-max
          }
          float mx = fmaxf(fmaxf(fmaxf(l0,l1), fmaxf(l2,l3)), l4v);
          float se = 0.f;
          #pragma unroll
          for (int o = 0; o < 5; ++o) se += __expf(lv[o] - mx);
          float lse = mx + __logf(se);
          float cur = lse - lop;
          lp  += cur;
          ent += cur * __expf(-cur);
          op_lds[gG][r] = op;
          out[2*BTOT + (size_t)(t-1)*BTOT + row0 + gG*GR + r] = (float)op;
        }
      }
    } else {
      // =============== E-crew (waves 4..7) ===============
      // gumbel u loads issued first so HBM latency hides under the tasks
      float upr[5];
      const bool gum = gnDo && et >= 240;
      if (gum){
        const float* up = u + ((size_t)uT*BTOT + row0 + gE*GR + (et-240))*5;
        #pragma unroll
        for (int o = 0; o < 5; ++o) upr[o] = up[o];
      }
      if (doE){
        #pragma unroll
        for (int tk = 0; tk < 2; ++tk){
          int task;
          if (tk == 0) task = (et < 192) ? et : (et < 208 ? et + 192 : -1);
          else         task = (et < 192) ? et + 192 : -1;
          if (task >= 0){
            const int jg = task >> 4, r = task & 15, c0s = jg*4;
            const float* zr = &zh[gE][r*ZW + c0s];
            f32x4 zg[4];
            #pragma unroll
            for (int g = 0; g < 4; ++g)
              zg[g] = *(const f32x4*)&zr[g*HH];
            if (addE){
              const int op = op_lds[gE][r];
              #pragma unroll
              for (int i = 0; i < 4; ++i){
                f32x4 e4 = *(const f32x4*)&Ep2_l[op*G4 + (c0s + i)*4];
                zg[0][i] += e4.x; zg[1][i] += e4.y; zg[2][i] += e4.z; zg[3][i] += e4.w;
              }
            }
            float hv[4];
            #pragma unroll
            for (int i = 0; i < 4; ++i){
              float cn_ = sigf(zg[1][i])*cs[tk][i] + sigf(zg[0][i])*tanh_f(zg[2][i]);
              cs[tk][i] = cn_;
              hv[i] = sigf(zg[3][i])*tanh_f(cn_);
            }
            if (jg < 24){                            // cells <96 -> bf16 hi/lo frags
              bfx4 h4, l4;
              #pragma unroll
              for (int i = 0; i < 4; ++i){
                unsigned short hi = bf16hi(hv[i]);
                h4[i] = (short)hi;
                l4[i] = (short)bf16hi(hv[i] - bf16f(hi));
              }
              const int kt   = jg >> 3;
              const int lf   = r | (((jg >> 1) & 3) << 4);
              const int j0   = (jg & 1) * 4;
              const int base = (kt*64 + lf)*8 + j0;
              *(bfx4*)&fhi[gE][base] = h4;
              *(bfx4*)&flo[gE][base] = l4;
            } else {                                 // cells 96..99 -> f32 residual
              #pragma unroll
              for (int i = 0; i < 4; ++i) h_res[gE][i*GR + r] = hv[i];
            }
          }
        }
      }
      if (gum){
        const int r = et - 240;
        #pragma unroll
        for (int o = 0; o < 5; ++o)
          gn_lds[gE][r*5 + o] = -__logf(-__logf(upr[o] + EPSF) + EPSF);
      }
    }
  };

  for (int t = 0; t <= TST; ++t){
    phase(0, t, csB, lpA, entA);   // G(A,t)+sample(A,t-1) || E(B,t-1)+gn(B)
    __syncthreads();
    phase(1, t, csA, lpB, entB);   // G(B,t)+sample(B,t-1) || E(A,t)+gn(A)
    if (t == TST) break;
    __syncthreads();
  }

  if (wave == 3 && lane < 16){
    out[row0 + lane]             = lpA;
    out[row0 + GR + lane]        = lpB;
    out[BTOT + row0 + lane]      = entA;
    out[BTOT + row0 + GR + lane] = entB;
  }
}

extern "C" void kernel_launch(void* const* d_in, const int* in_sizes, int n_in,
                              void* d_out, int out_size, void* d_ws, size_t ws_size,
                              hipStream_t stream) {
  const float* x0   = (const float*)d_in[0];
  const float* Wx   = (const float*)d_in[1];
  const float* Wh   = (const float*)d_in[2];
  const float* Wops = (const float*)d_in[3];
  const float* emb  = (const float*)d_in[4];
  const float* u    = (const float*)d_in[5];
  (void)d_ws; (void)ws_size; (void)in_sizes; (void)n_in;

  setup_bpack<<<(NTIL*KTN*64 + 255)/256, 256, 0, stream>>>(Wh, Wops);
  setup_misc<<<(6*G4 + NCOL*4 + 255)/256, 256, 0, stream>>>(emb, Wx, Wh, Wops);
  setup_z0<<<BTOT/64, 256, 0, stream>>>(x0, Wx);
  rnn_main<<<NBLK, BLOCK, 0, stream>>>(u, (float*)d_out);
}

// Round 6
// 2230.365 us; speedup vs baseline: 1.0329x; 1.0329x over previous
//
#include <hip/hip_runtime.h>
#include <cstdint>
#include <cstddef>

typedef __attribute__((ext_vector_type(8))) short short8;   // 8 bf16 (4 VGPRs)
typedef __attribute__((ext_vector_type(4))) short bfx4;     // 4 bf16 (8 B)
typedef __attribute__((ext_vector_type(4))) float f32x4;

#define HH     100
#define G4     400
#define NCOL   416          // 400 gates + 5 logits + 11 pad = 26 tiles of 16
#define NTIL   26
#define KTN    3            // 3 k-tiles of 32 -> k<96 via MFMA
#define KRES   96           // k=96..99 residual in f32
#define BTOT   8192
#define TST    512
#define GR     16           // rows per phase-group; block owns 2 groups = 32 rows
#define NBLK   256
#define BLOCK  512          // 8 waves; G-crew w0-3 (5 tiles ea), E-crew w4-7 (+6 tiles)
#define ZW     420          // z row stride; GR=16 -> uniform 2-way banks (free)
#define EPW    404          // Ep2 row stride; 6 ops -> 6 distinct start banks
#define TANHC  1.5f
#define EPSF   1e-9f

__device__ unsigned short d_Bhi[NTIL*KTN*64*8];  // [W_h|W_ops|0] hi, B-frag order
__device__ unsigned short d_Blo[NTIL*KTN*64*8];  // lo residual
__device__ float d_Ep2[6*EPW];                   // emb @ W_x   [e][cell][gate]
__device__ float d_WresG[NCOL*4];                // rows 96..99 of [W_h|W_ops|0], [n][q]
__device__ float d_Z0[(size_t)BTOT*G4];          // x0 @ W_x    [b][n]

static __device__ __forceinline__ unsigned short bf16hi(float f){
  unsigned u = __float_as_uint(f);
  return (unsigned short)((u + 0x7FFFu + ((u>>16)&1u)) >> 16);   // RNE
}
static __device__ __forceinline__ float bf16f(unsigned short s){
  return __uint_as_float(((unsigned)s)<<16);
}
static __device__ __forceinline__ float frcp(float x){ return __builtin_amdgcn_rcpf(x); }
static __device__ __forceinline__ float sigf(float x){ return frcp(1.0f + __expf(-x)); }
static __device__ __forceinline__ float tanh_f(float x){ return 1.0f - 2.0f*frcp(__expf(2.0f*x) + 1.0f); }

// ---- setup kernels -------------------------------------------------------

// B-frag order for 16x16x32: n = tile*16 + (lane&15), k = kt*32 + (lane>>4)*8 + i
__global__ void setup_bpack(const float* __restrict__ Wh, const float* __restrict__ Wops){
  int idx = blockIdx.x*blockDim.x + threadIdx.x;     // NTIL*KTN*64 = 4992
  if (idx >= NTIL*KTN*64) return;
  int tile = idx/(KTN*64), rem = idx - tile*(KTN*64), kt = rem>>6, ln = rem&63;
  int n = tile*16 + (ln & 15);
  #pragma unroll
  for (int i = 0; i < 8; ++i){
    int k = kt*32 + (ln>>4)*8 + i;                   // k < 96 always
    float w = 0.f;
    if (n < G4)          w = Wh[k*G4 + n];
    else if (n < G4+5)   w = Wops[k*5 + (n - G4)];
    unsigned short hi = bf16hi(w);
    unsigned short lo = bf16hi(w - bf16f(hi));
    d_Bhi[idx*8+i] = hi;
    d_Blo[idx*8+i] = lo;
  }
}

__global__ void setup_misc(const float* __restrict__ emb, const float* __restrict__ Wx,
                           const float* __restrict__ Wh, const float* __restrict__ Wops){
  int idx = blockIdx.x*blockDim.x + threadIdx.x;
  if (idx < 6*EPW){                                  // Ep2 [e][cell][gate], stride EPW
    int e = idx/EPW, r2 = idx - e*EPW, je = r2>>2, g = r2&3;
    float s = 0.f;
    if (je < HH)
      for (int k = 0; k < HH; ++k) s = fmaf(emb[e*HH+k], Wx[k*G4 + g*HH + je], s);
    d_Ep2[idx] = s;
  } else if (idx < 6*EPW + NCOL*4){                  // residual rows 96..99
    int i = idx - 6*EPW, n = i>>2, q = i&3;
    float w = 0.f;
    if (n < G4)        w = Wh[(KRES+q)*G4 + n];
    else if (n < G4+5) w = Wops[(KRES+q)*5 + (n - G4)];
    d_WresG[i] = w;
  }
}

// Z0 = x0 @ W_x, stored [b][n]
__global__ __launch_bounds__(256) void setup_z0(const float* __restrict__ x0,
                                                const float* __restrict__ Wx){
  __shared__ float xs[64*101];
  const int bb = blockIdx.x * 64;                    // 128 blocks
  for (int i = threadIdx.x; i < 64*HH; i += 256){
    int r = i/HH, k = i - r*HH;
    xs[r*101 + k] = x0[(size_t)(bb + r)*HH + k];
  }
  __syncthreads();
  const int bl = threadIdx.x & 63;
  for (int ng = threadIdx.x >> 6; ng < HH; ng += 4){
    f32x4 a = {0.f,0.f,0.f,0.f};
    for (int k = 0; k < HH; ++k){
      f32x4 w = *(const f32x4*)&Wx[k*G4 + ng*4];
      a += w * xs[bl*101 + k];
    }
    *(f32x4*)&d_Z0[(size_t)(bb + bl)*G4 + ng*4] = a;
  }
}

// ---- main persistent kernel ---------------------------------------------
// 256 blocks x 32 rows (A=rows 0..15, B=16..31), 8 waves, wave-specialized
// WITH a spill-proof register budget (r5 lesson: 7 tiles/wave = 296 regs ->
// forced spill, WRITE_SIZE 2x):
//   G-crew w0-3: 5 B-tiles each in regs (120) -> ~230 total <= 256 budget.
//   E-crew w4-7: LSTM elementwise for the other group + the 6 leftover tiles
//     (w4:20,21  w5:22,23  w6:24  w7: tile 25 SWAPPED + sampler, r3-verified).
// Each SIMD hosts 1 G-wave + 1 E-wave -> MFMA/VALU co-issue (m114).
//   phase(0,t): G(A,t)+sample(A,t-1)  ||  E(B,t-1) + gn(B,u[t-1])
//   phase(1,t): G(B,t)+sample(B,t-1)  ||  E(A,t)   + gn(A,u[t])

__global__ __launch_bounds__(BLOCK, 2) void rnn_main(
    const float* __restrict__ u, float* __restrict__ out)
{
  __shared__ __align__(16) float zh[2][GR*ZW];                  // 53760 B
  __shared__ __align__(16) unsigned short fhi[2][KTN*64*8];     //  6144 B
  __shared__ __align__(16) unsigned short flo[2][KTN*64*8];     //  6144 B
  __shared__ __align__(16) float h_res[2][GR*4];                //   512 B [r][q]
  __shared__ __align__(16) float Ep2_l[6*EPW];                  //  9696 B
  __shared__ __align__(16) float Wres_l[NCOL*4];                //  6656 B
  __shared__ __align__(16) float gn_lds[2][GR*5];               //   640 B
  __shared__ int op_lds[2][GR];                                 //   128 B

  const int tid  = threadIdx.x;
  const int wave = tid >> 6;
  const int lane = tid & 63;
  const int cn   = lane & 15;
  const int q4   = lane >> 4;
  const int row0 = blockIdx.x * (2*GR);
  const int et   = tid - 256;       // E-crew index (waves 4..7)

  for (int i = tid; i < 6*EPW;  i += BLOCK) Ep2_l[i]  = d_Ep2[i];
  for (int i = tid; i < NCOL*4; i += BLOCK) Wres_l[i] = d_WresG[i];

  // persistent B-fragments: w0-3: tiles 5w..5w+4; w4:20,21 w5:22,23 w6:24 w7:25
  const int tb  = (wave < 4) ? wave*5 : (wave==4 ? 20 : wave==5 ? 22 : wave==6 ? 24 : 25);
  const int ntl = (wave < 4) ? 5 : (wave <= 5 ? 2 : 1);
  short8 bh[5][KTN], bl[5][KTN];
  {
    const short8* bph = (const short8*)d_Bhi;
    const short8* bpl = (const short8*)d_Blo;
    #pragma unroll
    for (int tl = 0; tl < 5; ++tl) if (tl < ntl)
      #pragma unroll
      for (int kt = 0; kt < KTN; ++kt){
        int fi = ((tb+tl)*KTN + kt)*64 + lane;
        bh[tl][kt] = bph[fi];
        bl[tl][kt] = bpl[fi];
      }
  }

  float csA[2][4] = {{0.f,0.f,0.f,0.f},{0.f,0.f,0.f,0.f}};  // c-state [task][cell]
  float csB[2][4] = {{0.f,0.f,0.f,0.f},{0.f,0.f,0.f,0.f}};
  float lpA=0.f, entA=0.f, lpB=0.f, entB=0.f;

  __syncthreads();

  // one LSTM 4-cell task (round-4/5 verified math; h_res layout [r][q])
  auto etask = [&](int jg, int r, float (&cst)[4], bool addE_, int gE_){
    const int c0s = jg*4;
    const float* zr = &zh[gE_][r*ZW + c0s];
    f32x4 zg[4];
    #pragma unroll
    for (int g = 0; g < 4; ++g) zg[g] = *(const f32x4*)&zr[g*HH];
    if (addE_){
      const int op = op_lds[gE_][r];
      #pragma unroll
      for (int i = 0; i < 4; ++i){
        f32x4 e4 = *(const f32x4*)&Ep2_l[op*EPW + (c0s + i)*4];
        zg[0][i] += e4.x; zg[1][i] += e4.y; zg[2][i] += e4.z; zg[3][i] += e4.w;
      }
    }
    float hv[4];
    #pragma unroll
    for (int i = 0; i < 4; ++i){
      float cn_ = sigf(zg[1][i])*cst[i] + sigf(zg[0][i])*tanh_f(zg[2][i]);
      cst[i] = cn_;
      hv[i] = sigf(zg[3][i])*tanh_f(cn_);
    }
    if (jg < 24){                                    // cells <96 -> bf16 hi/lo frags
      bfx4 h4, l4;
      #pragma unroll
      for (int i = 0; i < 4; ++i){
        unsigned short hi = bf16hi(hv[i]);
        h4[i] = (short)hi;
        l4[i] = (short)bf16hi(hv[i] - bf16f(hi));
      }
      const int kt   = jg >> 3;
      const int lf   = r | (((jg >> 1) & 3) << 4);
      const int j0   = (jg & 1) * 4;
      const int base = (kt*64 + lf)*8 + j0;
      *(bfx4*)&fhi[gE_][base] = h4;
      *(bfx4*)&flo[gE_][base] = l4;
    } else {                                         // cells 96..99 -> f32 residual
      f32x4 hr4 = {hv[0], hv[1], hv[2], hv[3]};
      *(f32x4*)&h_res[gE_][r*4] = hr4;
    }
  };

  auto phase = [&](int gG, int t, float (&cs)[2][4], float& lp, float& ent){
    const int  gE    = gG ^ 1;
    const bool stage = (t == 0);
    const bool doE   = gG ? (t < TST) : (t >= 1);
    const bool addE  = gG ? (t >= 1)  : (t >= 2);
    const bool gnDo  = gG ? (t < TST) : (t >= 1);
    const int  uT    = gG ? t : (t-1);

    if (wave < 4){
      // =============== G-crew: 5 tiles each ===============
      if (stage){
        for (int k = tid; k < GR*HH; k += 256){
          int r = k/HH, c4 = k - r*HH;
          *(f32x4*)&zh[gG][r*ZW + c4*4] =
            *(const f32x4*)&d_Z0[(size_t)(row0 + gG*GR + r)*G4 + c4*4];
        }
      } else {
        short8 ah[KTN], al[KTN];
        #pragma unroll
        for (int kt = 0; kt < KTN; ++kt){
          ah[kt] = *(const short8*)&fhi[gG][(kt*64 + lane)*8];
          al[kt] = *(const short8*)&flo[gG][(kt*64 + lane)*8];
        }
        f32x4 hq[4];
        #pragma unroll
        for (int i = 0; i < 4; ++i)                  // broadcast reads [r][q]
          hq[i] = *(const f32x4*)&h_res[gG][(q4*4+i)*4];
        #pragma unroll
        for (int tl = 0; tl < 5; ++tl){
          const int n = (tb+tl)*16 + cn;
          f32x4 acc = {0.f,0.f,0.f,0.f};
          #pragma unroll
          for (int kt = 0; kt < KTN; ++kt){
            acc = __builtin_amdgcn_mfma_f32_16x16x32_bf16(ah[kt], bh[tl][kt], acc, 0,0,0);
            acc = __builtin_amdgcn_mfma_f32_16x16x32_bf16(al[kt], bh[tl][kt], acc, 0,0,0);
            acc = __builtin_amdgcn_mfma_f32_16x16x32_bf16(ah[kt], bl[tl][kt], acc, 0,0,0);
            acc = __builtin_amdgcn_mfma_f32_16x16x32_bf16(al[kt], bl[tl][kt], acc, 0,0,0);
          }
          f32x4 wr = *(const f32x4*)&Wres_l[n*4];
          #pragma unroll
          for (int i = 0; i < 4; ++i)
            acc[i] += hq[i].x*wr.x + hq[i].y*wr.y + hq[i].z*wr.z + hq[i].w*wr.w;
          #pragma unroll
          for (int i = 0; i < 4; ++i)                // C: row=q4*4+i, col=n
            zh[gG][(q4*4+i)*ZW + n] = acc[i];
        }
      }
    } else {
      // =============== E-crew (waves 4..7) ===============
      float upr[5];
      const bool gum = gnDo && et >= 240;            // wave 7 lanes 48..63
      if (gum){
        const float* up = u + ((size_t)uT*BTOT + row0 + gE*GR + (et-240))*5;
        #pragma unroll
        for (int o = 0; o < 5; ++o) upr[o] = up[o];
      }
      if (doE){
        etask(et >> 4, et & 15, cs[0], addE, gE);            // task1: jg 0..15
        if (et < 144)
          etask(16 + (et >> 4), et & 15, cs[1], addE, gE);   // task2: jg 16..24
      }
      if (!stage){
        short8 ah[KTN], al[KTN];                     // A-frags of group gG
        #pragma unroll
        for (int kt = 0; kt < KTN; ++kt){
          ah[kt] = *(const short8*)&fhi[gG][(kt*64 + lane)*8];
          al[kt] = *(const short8*)&flo[gG][(kt*64 + lane)*8];
        }
        if (wave < 7){
          // leftover gate tiles (w4:2, w5:2, w6:1)
          f32x4 hq[4];
          #pragma unroll
          for (int i = 0; i < 4; ++i)
            hq[i] = *(const f32x4*)&h_res[gG][(q4*4+i)*4];
          #pragma unroll
          for (int tl = 0; tl < 2; ++tl) if (tl < ntl){
            const int n = (tb+tl)*16 + cn;
            f32x4 acc = {0.f,0.f,0.f,0.f};
            #pragma unroll
            for (int kt = 0; kt < KTN; ++kt){
              acc = __builtin_amdgcn_mfma_f32_16x16x32_bf16(ah[kt], bh[tl][kt], acc, 0,0,0);
              acc = __builtin_amdgcn_mfma_f32_16x16x32_bf16(al[kt], bh[tl][kt], acc, 0,0,0);
              acc = __builtin_amdgcn_mfma_f32_16x16x32_bf16(ah[kt], bl[tl][kt], acc, 0,0,0);
              acc = __builtin_amdgcn_mfma_f32_16x16x32_bf16(al[kt], bl[tl][kt], acc, 0,0,0);
            }
            f32x4 wr = *(const f32x4*)&Wres_l[n*4];
            #pragma unroll
            for (int i = 0; i < 4; ++i)
              acc[i] += hq[i].x*wr.x + hq[i].y*wr.y + hq[i].z*wr.z + hq[i].w*wr.w;
            #pragma unroll
            for (int i = 0; i < 4; ++i)
              zh[gG][(q4*4+i)*ZW + n] = acc[i];
          }
        } else {
          // wave 7: logits tile 25 SWAPPED (r3-verified) + sampling for (gG,t-1)
          f32x4 accT = {0.f,0.f,0.f,0.f};
          #pragma unroll
          for (int kt = 0; kt < KTN; ++kt){          // term order = normal path
            accT = __builtin_amdgcn_mfma_f32_16x16x32_bf16(bh[0][kt], ah[kt], accT, 0,0,0);
            accT = __builtin_amdgcn_mfma_f32_16x16x32_bf16(bh[0][kt], al[kt], accT, 0,0,0);
            accT = __builtin_amdgcn_mfma_f32_16x16x32_bf16(bl[0][kt], ah[kt], accT, 0,0,0);
            accT = __builtin_amdgcn_mfma_f32_16x16x32_bf16(bl[0][kt], al[kt], accT, 0,0,0);
          }
          f32x4 hr = *(const f32x4*)&h_res[gG][cn*4];
          #pragma unroll
          for (int i = 0; i < 4; ++i){
            f32x4 wr = *(const f32x4*)&Wres_l[(G4 + q4*4 + i)*4];  // rows >404 are 0
            accT[i] += hr.x*wr.x + hr.y*wr.y + hr.z*wr.z + hr.w*wr.w;
          }
          float l4raw = __shfl_down(accT[0], 16);    // o=4 lives in lane r+16, reg 0
          if (lane < 16){
            const int r = lane;
            float lv[5];
            lv[0] = TANHC*tanh_f(accT[0]);
            lv[1] = TANHC*tanh_f(accT[1]);
            lv[2] = TANHC*tanh_f(accT[2]);
            lv[3] = TANHC*tanh_f(accT[3]);
            lv[4] = TANHC*tanh_f(l4raw);
            int op = 0; float best = -1e30f, lop = lv[0];
            #pragma unroll
            for (int o = 0; o < 5; ++o){
              float v = lv[o] + gn_lds[gG][r*5 + o];
              if (v > best){ best = v; op = o; lop = lv[o]; } // strict >: first-max
            }
            float mx = fmaxf(fmaxf(fmaxf(lv[0],lv[1]), fmaxf(lv[2],lv[3])), lv[4]);
            float se = 0.f;
            #pragma unroll
            for (int o = 0; o < 5; ++o) se += __expf(lv[o] - mx);
            float lse = mx + __logf(se);
            float cur = lse - lop;
            lp  += cur;
            ent += cur * __expf(-cur);
            op_lds[gG][r] = op;
            out[2*BTOT + (size_t)(t-1)*BTOT + row0 + gG*GR + r] = (float)op;
          }
        }
      }
      if (gum){
        const int r = et - 240;
        #pragma unroll
        for (int o = 0; o < 5; ++o)
          gn_lds[gE][r*5 + o] = -__logf(-__logf(upr[o] + EPSF) + EPSF);
      }
    }
  };

  for (int t = 0; t <= TST; ++t){
    phase(0, t, csB, lpA, entA);   // G(A,t)+sample(A,t-1) || E(B,t-1)+gn(B)
    __syncthreads();
    phase(1, t, csA, lpB, entB);   // G(B,t)+sample(B,t-1) || E(A,t)+gn(A)
    if (t == TST) break;
    __syncthreads();
  }

  if (wave == 7 && lane < 16){
    out[row0 + lane]             = lpA;
    out[row0 + GR + lane]        = lpB;
    out[BTOT + row0 + lane]      = entA;
    out[BTOT + row0 + GR + lane] = entB;
  }
}

extern "C" void kernel_launch(void* const* d_in, const int* in_sizes, int n_in,
                              void* d_out, int out_size, void* d_ws, size_t ws_size,
                              hipStream_t stream) {
  const float* x0   = (const float*)d_in[0];
  const float* Wx   = (const float*)d_in[1];
  const float* Wh   = (const float*)d_in[2];
  const float* Wops = (const float*)d_in[3];
  const float* emb  = (const float*)d_in[4];
  const float* u    = (const float*)d_in[5];
  (void)d_ws; (void)ws_size; (void)in_sizes; (void)n_in;

  setup_bpack<<<(NTIL*KTN*64 + 255)/256, 256, 0, stream>>>(Wh, Wops);
  setup_misc<<<(6*EPW + NCOL*4 + 255)/256, 256, 0, stream>>>(emb, Wx, Wh, Wops);
  setup_z0<<<BTOT/64, 256, 0, stream>>>(x0, Wx);
  rnn_main<<<NBLK, BLOCK, 0, stream>>>(u, (float*)d_out);
}

// Round 7
// 1986.180 us; speedup vs baseline: 1.1599x; 1.1229x over previous
//
#include <hip/hip_runtime.h>
#include <cstdint>
#include <cstddef>

typedef __attribute__((ext_vector_type(8))) short short8;   // 8 bf16 (4 VGPRs)
typedef __attribute__((ext_vector_type(4))) short bfx4;     // 4 bf16 (8 B)
typedef __attribute__((ext_vector_type(4))) float f32x4;

#define HH     100
#define G4     400
#define NCOL   416          // 400 gates + 5 logits + 11 pad = 26 tiles of 16
#define NTIL   26
#define KTN    3            // 3 k-tiles of 32 -> k<96 via MFMA
#define KRES   96           // k=96..99 residual in f32
#define BTOT   8192
#define TST    512
#define ROWS   32
#define NBLK   256
#define BLOCK  512          // 8 waves x 64; 2 waves/SIMD -> 256-reg budget/wave
#define ZW     420          // z_lds row stride (words)
#define TANHC  1.5f
#define EPSF   1e-9f

__device__ unsigned short d_Bhi[NTIL*KTN*64*8];  // [W_h|W_ops|0] hi, B-frag order
__device__ unsigned short d_Blo[NTIL*KTN*64*8];  // lo residual
__device__ float d_Ep2[6*G4];                    // emb @ W_x   [e][cell][gate]
__device__ float d_WresG[NCOL*4];                // rows 96..99 of [W_h|W_ops|0], [n][q]
__device__ float d_Z0[(size_t)BTOT*G4];          // x0 @ W_x    [b][n]

static __device__ __forceinline__ unsigned short bf16hi(float f){
  unsigned u = __float_as_uint(f);
  return (unsigned short)((u + 0x7FFFu + ((u>>16)&1u)) >> 16);   // RNE
}
static __device__ __forceinline__ float bf16f(unsigned short s){
  return __uint_as_float(((unsigned)s)<<16);
}
static __device__ __forceinline__ float frcp(float x){ return __builtin_amdgcn_rcpf(x); }
static __device__ __forceinline__ float sigf(float x){ return frcp(1.0f + __expf(-x)); }
static __device__ __forceinline__ float tanh_f(float x){ return 1.0f - 2.0f*frcp(__expf(2.0f*x) + 1.0f); }

// ---- setup kernels (round-0 verbatim) ------------------------------------

// B-frag order for 16x16x32: n = tile*16 + (lane&15), k = kt*32 + (lane>>4)*8 + i
__global__ void setup_bpack(const float* __restrict__ Wh, const float* __restrict__ Wops){
  int idx = blockIdx.x*blockDim.x + threadIdx.x;     // NTIL*KTN*64 = 4992
  if (idx >= NTIL*KTN*64) return;
  int tile = idx/(KTN*64), rem = idx - tile*(KTN*64), kt = rem>>6, ln = rem&63;
  int n = tile*16 + (ln & 15);
  #pragma unroll
  for (int i = 0; i < 8; ++i){
    int k = kt*32 + (ln>>4)*8 + i;                   // k < 96 always
    float w = 0.f;
    if (n < G4)          w = Wh[k*G4 + n];
    else if (n < G4+5)   w = Wops[k*5 + (n - G4)];
    unsigned short hi = bf16hi(w);
    unsigned short lo = bf16hi(w - bf16f(hi));
    d_Bhi[idx*8+i] = hi;
    d_Blo[idx*8+i] = lo;
  }
}

__global__ void setup_misc(const float* __restrict__ emb, const float* __restrict__ Wx,
                           const float* __restrict__ Wh, const float* __restrict__ Wops){
  int idx = blockIdx.x*blockDim.x + threadIdx.x;
  if (idx < 6*G4){                                   // Ep2 [e][cell][gate]
    int e = idx/G4, r2 = idx - e*G4, je = r2>>2, g = r2&3;
    float s = 0.f;
    for (int k = 0; k < HH; ++k) s = fmaf(emb[e*HH+k], Wx[k*G4 + g*HH + je], s);
    d_Ep2[idx] = s;
  } else if (idx < 6*G4 + NCOL*4){                   // residual rows 96..99
    int i = idx - 6*G4, n = i>>2, q = i&3;
    float w = 0.f;
    if (n < G4)        w = Wh[(KRES+q)*G4 + n];
    else if (n < G4+5) w = Wops[(KRES+q)*5 + (n - G4)];
    d_WresG[i] = w;
  }
}

// Z0 = x0 @ W_x, stored [b][n]
__global__ __launch_bounds__(256) void setup_z0(const float* __restrict__ x0,
                                                const float* __restrict__ Wx){
  __shared__ float xs[64*101];
  const int bb = blockIdx.x * 64;                    // 128 blocks
  for (int i = threadIdx.x; i < 64*HH; i += 256){
    int r = i/HH, k = i - r*HH;
    xs[r*101 + k] = x0[(size_t)(bb + r)*HH + k];
  }
  __syncthreads();
  const int bl = threadIdx.x & 63;
  for (int ng = threadIdx.x >> 6; ng < HH; ng += 4){
    f32x4 a = {0.f,0.f,0.f,0.f};
    for (int k = 0; k < HH; ++k){
      f32x4 w = *(const f32x4*)&Wx[k*G4 + ng*4];
      a += w * xs[bl*101 + k];
    }
    *(f32x4*)&d_Z0[(size_t)(bb + bl)*G4 + ng*4] = a;
  }
}

// ---- main persistent kernel ---------------------------------------------
// r4 base (best: 2081us) with three cuts:
//  (1) 3-term bf16x2 MFMA (drop lo*lo): 9 MFMA/tile instead of 12.
//  (2) wave 0: tiles 23,24 normal + tile 25 SWAPPED (mfma(W,h) -> logits in
//      regs; r3/r6-verified form). Sampler reads registers, no samp LDS
//      round-trip. Rows 0-15 from accT[0], 16-31 from accT[1] via 5 shfls.
//  (3) op_lds read hoisted above both E passes.

__global__ __launch_bounds__(BLOCK, 2) void rnn_main(
    const float* __restrict__ u, float* __restrict__ out)
{
  __shared__ __align__(16) float z_lds[ROWS*ZW];                // 53760 B
  __shared__ __align__(16) unsigned short fhi[2*KTN*64*8];      //  6144 B
  __shared__ __align__(16) unsigned short flo[2*KTN*64*8];      //  6144 B
  __shared__ __align__(16) float h_res[4*ROWS];                 //   512 B [q][r]
  __shared__ __align__(16) float Ep2_l[6*G4];                   //  9600 B
  __shared__ __align__(16) float Wres_l[NCOL*4];                //  6656 B
  __shared__ __align__(16) float gn_lds[ROWS*5];                //   640 B
  __shared__ int op_lds[ROWS];

  const int tid  = threadIdx.x;
  const int wave = tid >> 6;
  const int lane = tid & 63;
  const int cn   = lane & 15;       // col-in-tile (B,C) / row-in-tile (A)
  const int q4   = lane >> 4;       // quad
  const int row0 = blockIdx.x * ROWS;
  const int rE   = tid & 31;        // E row

  for (int i = tid; i < 6*G4;   i += BLOCK) Ep2_l[i]  = d_Ep2[i];
  for (int i = tid; i < NCOL*4; i += BLOCK) Wres_l[i] = d_WresG[i];

  // persistent B-fragments, 3-4 tiles per wave (wave0: 23,24 normal + 25 swapped)
  const int tb  = (wave==0) ? 23 : (wave < 6) ? 3*(wave-1) : 15 + 4*(wave-6);
  const int ntl = (wave >= 6) ? 4 : 3;               // tiles LOADED
  const int ngt = (wave == 0) ? 2 : ntl;             // tiles computed normally
  short8 bh[4][KTN], bl[4][KTN];
  {
    const short8* bph = (const short8*)d_Bhi;
    const short8* bpl = (const short8*)d_Blo;
    #pragma unroll
    for (int tl = 0; tl < 4; ++tl) if (tl < ntl)
      #pragma unroll
      for (int kt = 0; kt < KTN; ++kt){
        int fi = ((tb+tl)*KTN + kt)*64 + lane;
        bh[tl][kt] = bph[fi];
        bl[tl][kt] = bpl[fi];
      }
  }

  float cs1[4] = {0.f,0.f,0.f,0.f};   // pass-1 cells (jg 0..15)
  float cs2[4] = {0.f,0.f,0.f,0.f};   // pass-2 cells (jg 16..24)
  float lp_acc = 0.f, ent_acc = 0.f;

  for (int t = 0; t <= TST; ++t){
    // gumbel u prefetch (tid 416..447); HBM latency hides under G+E
    float upr[5];
    if (t < TST && tid >= 416 && tid < 448){
      const float* up = u + ((size_t)t*BTOT + row0 + (tid - 416))*5;
      #pragma unroll
      for (int o = 0; o < 5; ++o) upr[o] = up[o];
    }

    if (t == 0){
      // stage z_0 = x0 @ W_x (gates only)
      for (int i = tid; i < ROWS*HH; i += BLOCK){
        int r = i/HH, c4 = i - r*HH;
        *(f32x4*)&z_lds[r*ZW + c4*4] =
          *(const f32x4*)&d_Z0[(size_t)(row0 + r)*G4 + c4*4];
      }
    } else {
      // ---- G: z_t = h_t @ [W_h|W_ops]  (3-term MFMA k<96 + f32 residual) ----
      f32x4 accT[2];                                  // wave0: swapped logits tile
      #pragma unroll
      for (int mt = 0; mt < 2; ++mt){
        short8 ah[KTN], al[KTN];
        #pragma unroll
        for (int kt = 0; kt < KTN; ++kt){
          ah[kt] = *(const short8*)&fhi[((mt*KTN + kt)*64 + lane)*8];
          al[kt] = *(const short8*)&flo[((mt*KTN + kt)*64 + lane)*8];
        }
        f32x4 hq[4];
        #pragma unroll
        for (int q = 0; q < 4; ++q)                       // broadcast reads
          hq[q] = *(const f32x4*)&h_res[q*ROWS + mt*16 + q4*4];
        #pragma unroll
        for (int tl = 0; tl < 4; ++tl) if (tl < ngt){
          const int n = (tb+tl)*16 + cn;
          f32x4 acc = {0.f,0.f,0.f,0.f};
          #pragma unroll
          for (int kt = 0; kt < KTN; ++kt){
            acc = __builtin_amdgcn_mfma_f32_16x16x32_bf16(ah[kt], bh[tl][kt], acc, 0,0,0);
            acc = __builtin_amdgcn_mfma_f32_16x16x32_bf16(al[kt], bh[tl][kt], acc, 0,0,0);
            acc = __builtin_amdgcn_mfma_f32_16x16x32_bf16(ah[kt], bl[tl][kt], acc, 0,0,0);
          }
          f32x4 wr = *(const f32x4*)&Wres_l[n*4];
          #pragma unroll
          for (int q = 0; q < 4; ++q) acc += hq[q] * wr[q];
          const int rowb = mt*16 + q4*4;                  // C: row=q4*4+reg, col=cn
          #pragma unroll
          for (int i = 0; i < 4; ++i)
            z_lds[(rowb + i)*ZW + n] = acc[i];
        }
        if (wave == 0){                                   // swapped tile 25, rows mt*16..
          f32x4 a = {0.f,0.f,0.f,0.f};
          #pragma unroll
          for (int kt = 0; kt < KTN; ++kt){
            a = __builtin_amdgcn_mfma_f32_16x16x32_bf16(bh[2][kt], ah[kt], a, 0,0,0);
            a = __builtin_amdgcn_mfma_f32_16x16x32_bf16(bh[2][kt], al[kt], a, 0,0,0);
            a = __builtin_amdgcn_mfma_f32_16x16x32_bf16(bl[2][kt], ah[kt], a, 0,0,0);
          }
          accT[mt] = a;
        }
      }
      // ---- sampling for step t-1 (wave 0; logits live in accT registers) ----
      if (wave == 0){
        #pragma unroll
        for (int mt = 0; mt < 2; ++mt){                   // f32 residual for logits
          const int rr = mt*16 + cn;
          float h0 = h_res[0*ROWS + rr], h1 = h_res[1*ROWS + rr];
          float h2 = h_res[2*ROWS + rr], h3 = h_res[3*ROWS + rr];
          #pragma unroll
          for (int i = 0; i < 4; ++i){
            f32x4 wr = *(const f32x4*)&Wres_l[(G4 + q4*4 + i)*4];  // rows >404 are 0
            accT[mt][i] += h0*wr.x + h1*wr.y + h2*wr.z + h3*wr.w;
          }
        }
        // rows 0-15: lane r has o0-3 in accT[0], o4 at lane r+16 reg0
        float o4lo = __shfl_down(accT[0][0], 16);
        // rows 16-31: lane 16+r has o4 in its own accT[1][0]; o0-3 at lane r
        float t1o0 = __shfl_up(accT[1][0], 16);
        float t1o1 = __shfl_up(accT[1][1], 16);
        float t1o2 = __shfl_up(accT[1][2], 16);
        float t1o3 = __shfl_up(accT[1][3], 16);
        if (lane < 32){
          const int r = lane;
          float raw[5];
          if (lane < 16){
            raw[0] = accT[0][0]; raw[1] = accT[0][1];
            raw[2] = accT[0][2]; raw[3] = accT[0][3]; raw[4] = o4lo;
          } else {
            raw[0] = t1o0; raw[1] = t1o1; raw[2] = t1o2; raw[3] = t1o3;
            raw[4] = accT[1][0];
          }
          float l[5];
          #pragma unroll
          for (int o = 0; o < 5; ++o) l[o] = TANHC * tanh_f(raw[o]);
          int op = 0; float best = -1e30f;
          #pragma unroll
          for (int o = 0; o < 5; ++o){
            float v = l[o] + gn_lds[r*5 + o];
            if (v > best){ best = v; op = o; }            // strict >: first-max ties
          }
          float mx = fmaxf(fmaxf(fmaxf(l[0],l[1]), fmaxf(l[2],l[3])), l[4]);
          float se = 0.f;
          #pragma unroll
          for (int o = 0; o < 5; ++o) se += __expf(l[o] - mx);
          float lse = mx + __logf(se);
          float cur = lse - l[op];
          lp_acc  += cur;
          ent_acc += cur * __expf(-cur);
          op_lds[r] = op;
          out[2*BTOT + (size_t)(t-1)*BTOT + row0 + r] = (float)op;
        }
      }
    }
    if (t == TST) break;
    __syncthreads();   // b1: z_t + op_{t-1} ready

    // ---- E: LSTM elementwise (r4 body), op hoisted above both passes ----
    const int opv = (t > 0) ? op_lds[rE] : 0;
    // pass 1: all threads, jg = tid>>5 in 0..15 (cells 0..63)
    {
      const int jg = tid >> 5;
      f32x4 zg[4];
      #pragma unroll
      for (int g = 0; g < 4; ++g)
        zg[g] = *(const f32x4*)&z_lds[rE*ZW + g*HH + jg*4];
      if (t > 0){
        #pragma unroll
        for (int i = 0; i < 4; ++i){
          f32x4 e4 = *(const f32x4*)&Ep2_l[opv*G4 + (jg*4 + i)*4];
          zg[0][i] += e4.x; zg[1][i] += e4.y; zg[2][i] += e4.z; zg[3][i] += e4.w;
        }
      }
      float hv[4];
      #pragma unroll
      for (int i = 0; i < 4; ++i){
        float cn_ = sigf(zg[1][i])*cs1[i] + sigf(zg[0][i])*tanh_f(zg[2][i]);
        cs1[i] = cn_;
        hv[i] = sigf(zg[3][i])*tanh_f(cn_);
      }
      bfx4 h4, l4;                                       // jg<16 -> always frags
      #pragma unroll
      for (int i = 0; i < 4; ++i){
        unsigned short hi = bf16hi(hv[i]);
        h4[i] = (short)hi;
        l4[i] = (short)bf16hi(hv[i] - bf16f(hi));
      }
      const int kt   = jg >> 3;
      const int lf   = (rE & 15) | (((jg >> 1) & 3) << 4);
      const int mt   = rE >> 4;
      const int j0   = (jg & 1) * 4;
      const int base = ((mt*KTN + kt)*64 + lf)*8 + j0;
      *(bfx4*)&fhi[base] = h4;
      *(bfx4*)&flo[base] = l4;
    }
    // pass 2: tid<256 -> jg 16..23 (frags); tid>=480 -> jg 24 (h_res);
    // tid 416..447 -> gumbel noise
    if (tid < 256 || tid >= 480){
      const int jg = (tid < 256) ? (16 + (tid >> 5)) : 24;
      const int c0 = jg*4;
      f32x4 zg[4];
      #pragma unroll
      for (int g = 0; g < 4; ++g)
        zg[g] = *(const f32x4*)&z_lds[rE*ZW + g*HH + c0];
      if (t > 0){
        #pragma unroll
        for (int i = 0; i < 4; ++i){
          f32x4 e4 = *(const f32x4*)&Ep2_l[opv*G4 + (c0 + i)*4];
          zg[0][i] += e4.x; zg[1][i] += e4.y; zg[2][i] += e4.z; zg[3][i] += e4.w;
        }
      }
      float hv[4];
      #pragma unroll
      for (int i = 0; i < 4; ++i){
        float cn_ = sigf(zg[1][i])*cs2[i] + sigf(zg[0][i])*tanh_f(zg[2][i]);
        cs2[i] = cn_;
        hv[i] = sigf(zg[3][i])*tanh_f(cn_);
      }
      if (tid < 256){                                    // jg 16..23 -> frags
        bfx4 h4, l4;
        #pragma unroll
        for (int i = 0; i < 4; ++i){
          unsigned short hi = bf16hi(hv[i]);
          h4[i] = (short)hi;
          l4[i] = (short)bf16hi(hv[i] - bf16f(hi));
        }
        const int kt   = jg >> 3;                        // = 2
        const int lf   = (rE & 15) | (((jg >> 1) & 3) << 4);
        const int mt   = rE >> 4;
        const int j0   = (jg & 1) * 4;
        const int base = ((mt*KTN + kt)*64 + lf)*8 + j0;
        *(bfx4*)&fhi[base] = h4;
        *(bfx4*)&flo[base] = l4;
      } else {                                           // jg==24: k=96..99 residual
        #pragma unroll
        for (int i = 0; i < 4; ++i) h_res[i*ROWS + rE] = hv[i];
      }
    } else if (tid >= 416 && tid < 448){
      // gumbel noise for u[t] (consumed at G_{t+1}); loads issued at loop top
      int r = tid - 416;
      #pragma unroll
      for (int o = 0; o < 5; ++o)
        gn_lds[r*5 + o] = -__logf(-__logf(upr[o] + EPSF) + EPSF);
    }
    __syncthreads();   // b2: h_{t+1} frags + h_res + gn ready
  }

  if (wave == 0 && lane < 32){
    out[row0 + lane]        = lp_acc;
    out[BTOT + row0 + lane] = ent_acc;
  }
}

extern "C" void kernel_launch(void* const* d_in, const int* in_sizes, int n_in,
                              void* d_out, int out_size, void* d_ws, size_t ws_size,
                              hipStream_t stream) {
  const float* x0   = (const float*)d_in[0];
  const float* Wx   = (const float*)d_in[1];
  const float* Wh   = (const float*)d_in[2];
  const float* Wops = (const float*)d_in[3];
  const float* emb  = (const float*)d_in[4];
  const float* u    = (const float*)d_in[5];
  (void)d_ws; (void)ws_size; (void)in_sizes; (void)n_in;

  setup_bpack<<<(NTIL*KTN*64 + 255)/256, 256, 0, stream>>>(Wh, Wops);
  setup_misc<<<(6*G4 + NCOL*4 + 255)/256, 256, 0, stream>>>(emb, Wx, Wh, Wops);
  setup_z0<<<BTOT/64, 256, 0, stream>>>(x0, Wx);
  rnn_main<<<NBLK, BLOCK, 0, stream>>>(u, (float*)d_out);
}